// Round 6
// baseline (4195.328 us; speedup 1.0000x reference)
//
#include <hip/hip_runtime.h>
#include <hip/hip_bf16.h>
#include <hip/hip_fp8.h>
#include <math.h>

#define H 32
#define SCB 1024

__device__ __forceinline__ unsigned f2bf(float f) {  // f32 -> bf16 bits, RNE
  unsigned u = __float_as_uint(f);
  return (u + 0x7fffu + ((u >> 16) & 1u)) >> 16;
}
__device__ __forceinline__ float bflo(unsigned p) { return __uint_as_float(p << 16); }
__device__ __forceinline__ float bfhi(unsigned p) { return __uint_as_float(p & 0xffff0000u); }

// f32 -> OCP e4m3fn byte (RNE, saturating) via HIP type
__device__ __forceinline__ unsigned f2q(float f) {
  __hip_fp8_e4m3 q(f);
  return (unsigned)q.__x;
}
// OCP e4m3fn byte -> f32, branchless manual decode
__device__ __forceinline__ float q2f(unsigned b) {
  unsigned s = (b >> 7) & 1u, e = (b >> 3) & 15u, m = b & 7u;
  float vn = __uint_as_float((s << 31) | ((e + 120u) << 23) | (m << 20));
  float vs = __uint_as_float((s << 31) | 0x3f800000u) * ((float)(int)m * (1.0f / 512.0f));
  return (e == 0u) ? vs : vn;
}

// h = x@Wn+bn ; pkh[half][n][cc] = {e4m3(h), e4m3(h@lnw0+lnb0 - h)}
__global__ void k_encode(const float* __restrict__ x, const float* __restrict__ Wn,
                         const float* __restrict__ bn, const float* __restrict__ lnw0,
                         const float* __restrict__ lnb0, float* __restrict__ h,
                         unsigned short* __restrict__ pk0, unsigned short* __restrict__ pk1,
                         int n, int fnode) {
  __shared__ float sw[H * H];
  int tid = threadIdx.x;
  for (int i = tid; i < H * H; i += blockDim.x) sw[i] = lnw0[i];
  __syncthreads();
  int gid = blockIdx.x * blockDim.x + tid;
  int node = gid >> 5, c = gid & 31;
  if (node >= n) return;
  float acc = bn[c];
  for (int k = 0; k < fnode; ++k)
    acc = fmaf(x[node * fnode + k], Wn[k * H + c], acc);
  h[node * H + c] = acc;
  float t = lnb0[c];
#pragma unroll
  for (int k = 0; k < H; ++k)
    t = fmaf(__shfl(acc, k, 32), sw[k * H + c], t);
  unsigned short v = (unsigned short)(f2q(acc) | (f2q(t - acc) << 8));
  unsigned short* ph = (c < 16) ? pk0 : pk1;
  ph[node * 16 + (c & 15)] = v;
}

// W2[l] = We @ le_w[l]  ([2,H]) ; b2[l] = be @ le_w[l] + le_b[l]
__global__ void k_fold(const float* __restrict__ We, const float* __restrict__ be,
                       const float* __restrict__ lew, const float* __restrict__ leb,
                       float* __restrict__ W2, float* __restrict__ b2, int L) {
  int gid = blockIdx.x * blockDim.x + threadIdx.x;
  if (gid >= L * H) return;
  int l = gid >> 5, c = gid & 31;
  const float* lw = lew + (size_t)l * H * H;
  float a0 = 0.f, a1 = 0.f, bb = leb[l * H + c];
  for (int j = 0; j < H; ++j) {
    float w = lw[j * H + c];
    a0 = fmaf(We[j], w, a0);
    a1 = fmaf(We[H + j], w, a1);
    bb = fmaf(be[j], w, bb);
  }
  W2[l * 2 * H + c] = a0;
  W2[l * 2 * H + H + c] = a1;
  b2[l * H + c] = bb;
}

__global__ void k_hist(const int* __restrict__ dst, unsigned* __restrict__ cnt, int e) {
  int i = blockIdx.x * blockDim.x + threadIdx.x;
  if (i < e) atomicAdd(&cnt[dst[i]], 1u);
}

// two-level scan: per-block exclusive + block sums
__global__ void k_scan1(const unsigned* __restrict__ cnt, unsigned* __restrict__ out,
                        unsigned* __restrict__ bsum, int n) {
  __shared__ unsigned s[SCB];
  int i = blockIdx.x * SCB + threadIdx.x;
  unsigned v = (i < n) ? cnt[i] : 0u;
  s[threadIdx.x] = v;
  __syncthreads();
  for (int off = 1; off < SCB; off <<= 1) {
    unsigned u = (threadIdx.x >= off) ? s[threadIdx.x - off] : 0u;
    __syncthreads();
    s[threadIdx.x] += u;
    __syncthreads();
  }
  if (i < n) out[i] = s[threadIdx.x] - v;
  if (threadIdx.x == SCB - 1) bsum[blockIdx.x] = s[SCB - 1];
}

__global__ void k_scan2(const unsigned* __restrict__ bsum, unsigned* __restrict__ boff,
                        unsigned* __restrict__ total_out, int nb) {
  __shared__ unsigned s[SCB];
  unsigned v = ((int)threadIdx.x < nb) ? bsum[threadIdx.x] : 0u;
  s[threadIdx.x] = v;
  __syncthreads();
  for (int off = 1; off < SCB; off <<= 1) {
    unsigned u = (threadIdx.x >= off) ? s[threadIdx.x - off] : 0u;
    __syncthreads();
    s[threadIdx.x] += u;
    __syncthreads();
  }
  if ((int)threadIdx.x < nb) boff[threadIdx.x] = s[threadIdx.x] - v;
  if (threadIdx.x == SCB - 1) *total_out = s[SCB - 1];
}

__global__ void k_scan3(unsigned* __restrict__ row_ptr, const unsigned* __restrict__ boff,
                        unsigned* __restrict__ fill, int n) {
  int i = blockIdx.x * blockDim.x + threadIdx.x;
  if (i >= n) return;
  unsigned v = row_ptr[i] + boff[i >> 10];
  row_ptr[i] = v;
  fill[i] = v;
}

// rec = {src, bf16(attr0) | bf16(attr1)<<16}
__global__ void k_scatter(const int* __restrict__ src, const int* __restrict__ dst,
                          const float* __restrict__ ea, unsigned* __restrict__ fill,
                          uint2* __restrict__ recs, int e) {
  int i = blockIdx.x * blockDim.x + threadIdx.x;
  if (i >= e) return;
  int d = dst[i];
  unsigned pos = atomicAdd(&fill[d], 1u);
  float2 a = ((const float2*)ea)[i];
  recs[pos] = make_uint2((unsigned)src[i], f2bf(a.x) | (f2bf(a.y) << 16));
}

// half-channel aggregation pass: 16 lanes per dst node, lane = channel-in-half.
// Gathers 32B pkh rows (L2-resident: 3.2MB), recs streamed non-temporally.
__global__ void __launch_bounds__(256) k_pass(
    const unsigned short* __restrict__ pkh,
    const unsigned* __restrict__ row_ptr, const unsigned long long* __restrict__ recs,
    const float* __restrict__ w0p, const float* __restrict__ w1p,
    const float* __restrict__ bbp, float* __restrict__ agg, int n) {
  int gid = blockIdx.x * blockDim.x + threadIdx.x;
  int node = gid >> 4, c = gid & 15;
  if (node >= n) return;
  float w0 = w0p[c], w1 = w1p[c], bb = bbp[c];
  unsigned s0 = row_ptr[node], s1 = row_ptr[node + 1];
  float acc = 0.f;
  for (unsigned i = s0; i < s1; i += 8) {
    unsigned long long rv[8];
    unsigned short p[8];
    float sc[8];
#pragma unroll
    for (int j = 0; j < 8; ++j) {
      unsigned idx = i + (unsigned)j;
      sc[j] = (idx < s1) ? 1.f : 0.f;
      idx = (idx < s1) ? idx : s0;
      rv[j] = __builtin_nontemporal_load(&recs[idx]);
    }
#pragma unroll
    for (int j = 0; j < 8; ++j)
      p[j] = pkh[(((unsigned)rv[j]) << 4) + c];
#pragma unroll
    for (int j = 0; j < 8; ++j) {
      unsigned at = (unsigned)(rv[j] >> 32);
      float ee = fmaf(bflo(at), w0, fmaf(bfhi(at), w1, bb));
      float xq = q2f((unsigned)p[j] & 255u);
      float uq = q2f((unsigned)p[j] >> 8);
      acc = fmaf(sc[j], fmaf(ee, uq, xq), acc);
    }
  }
  __builtin_nontemporal_store(acc, &agg[node * H + c]);  // agg pre-offset by half*16
}

// node update: out = relu([h, agg] @ luw + lub); produce next layer's pkh halves
__global__ void __launch_bounds__(256) k_update(
    const float* __restrict__ h, const float* __restrict__ agg,
    const float* __restrict__ luw, const float* __restrict__ lub,
    const float* __restrict__ lnw_next, const float* __restrict__ lnb_next,
    float* __restrict__ hout, unsigned short* __restrict__ pk0,
    unsigned short* __restrict__ pk1, int n) {
  __shared__ float sw[2 * H * H];
  __shared__ float swn[H * H];
  int tid = threadIdx.x;
  for (int i = tid; i < 2 * H * H; i += 256) sw[i] = luw[i];
  if (lnw_next)
    for (int i = tid; i < H * H; i += 256) swn[i] = lnw_next[i];
  __syncthreads();
  int gid = blockIdx.x * blockDim.x + tid;
  int node = gid >> 5, c = gid & 31;
  if (node >= n) return;
  float hc = h[node * H + c];
  float ac = __builtin_nontemporal_load(&agg[node * H + c]);
  float o = lub[c];
#pragma unroll
  for (int k = 0; k < H; ++k) {
    float hk = __shfl(hc, k, 32);
    float ak = __shfl(ac, k, 32);
    o = fmaf(hk, sw[k * H + c], o);
    o = fmaf(ak, sw[(H + k) * H + c], o);
  }
  o = fmaxf(o, 0.f);
  __builtin_nontemporal_store(o, &hout[node * H + c]);
  if (pk0) {
    float t = lnb_next[c];
#pragma unroll
    for (int k = 0; k < H; ++k)
      t = fmaf(__shfl(o, k, 32), swn[k * H + c], t);
    unsigned short v = (unsigned short)(f2q(o) | (f2q(t - o) << 8));
    unsigned short* ph = (c < 16) ? pk0 : pk1;
    ph[node * 16 + (c & 15)] = v;
  }
}

// classifier: sigmoid(relu(h@c1+b1)@c2 + b2)
__global__ void k_cls(const float* __restrict__ h, const float* __restrict__ c1w,
                      const float* __restrict__ c1b, const float* __restrict__ c2w,
                      const float* __restrict__ c2b, float* __restrict__ out, int n) {
  __shared__ float sw[H * H];
  int tid = threadIdx.x;
  for (int i = tid; i < H * H; i += blockDim.x) sw[i] = c1w[i];
  __syncthreads();
  int gid = blockIdx.x * blockDim.x + tid;
  int node = gid >> 5, c = gid & 31;
  if (node >= n) return;
  float hv = h[node * H + c];
  float z = c1b[c];
#pragma unroll
  for (int k = 0; k < H; ++k)
    z = fmaf(__shfl(hv, k, 32), sw[k * H + c], z);
  z = fmaxf(z, 0.f);
  float r = z * c2w[c];
#pragma unroll
  for (int m = 16; m >= 1; m >>= 1)
    r += __shfl_xor(r, m, 32);
  if (c == 0) out[node] = 1.f / (1.f + expf(-(r + c2b[0])));
}

extern "C" void kernel_launch(void* const* d_in, const int* in_sizes, int n_in,
                              void* d_out, int out_size, void* d_ws, size_t ws_size,
                              hipStream_t stream) {
  const float* x         = (const float*)d_in[0];
  const float* edge_attr = (const float*)d_in[1];
  const int*   edge_index= (const int*)d_in[2];
  const float* Wn        = (const float*)d_in[3];
  const float* bn        = (const float*)d_in[4];
  const float* We        = (const float*)d_in[5];
  const float* be        = (const float*)d_in[6];
  const float* ln_w      = (const float*)d_in[7];
  const float* ln_b      = (const float*)d_in[8];
  const float* le_w      = (const float*)d_in[9];
  const float* le_b      = (const float*)d_in[10];
  const float* lu_w      = (const float*)d_in[11];
  const float* lu_b      = (const float*)d_in[12];
  const float* c1w       = (const float*)d_in[13];
  const float* c1b       = (const float*)d_in[14];
  const float* c2w       = (const float*)d_in[15];
  const float* c2b       = (const float*)d_in[16];

  const int N_ = in_sizes[0] / 5;
  const int E_ = in_sizes[1] / 2;
  const int L_ = in_sizes[7] / (H * H);
  const int* src = edge_index;
  const int* dst = edge_index + E_;

  char* ws = (char*)d_ws;
  size_t off = 0;
  auto alloc = [&](size_t bytes) -> void* {
    void* p = ws + off;
    off = (off + bytes + 255) & ~(size_t)255;
    return p;
  };
  float*          hA      = (float*)alloc((size_t)N_ * H * 4);
  float*          hB      = (float*)alloc((size_t)N_ * H * 4);
  unsigned short* pkA0    = (unsigned short*)alloc((size_t)N_ * 16 * 2);
  unsigned short* pkA1    = (unsigned short*)alloc((size_t)N_ * 16 * 2);
  unsigned short* pkB0    = (unsigned short*)alloc((size_t)N_ * 16 * 2);
  unsigned short* pkB1    = (unsigned short*)alloc((size_t)N_ * 16 * 2);
  float*          agg     = (float*)alloc((size_t)N_ * H * 4);
  unsigned*       row_ptr = (unsigned*)alloc((size_t)(N_ + 1) * 4);
  unsigned*       fill    = (unsigned*)alloc((size_t)N_ * 4);
  uint2*          recs    = (uint2*)alloc((size_t)E_ * 8);
  float*          W2      = (float*)alloc((size_t)L_ * 2 * H * 4);
  float*          b2      = (float*)alloc((size_t)L_ * H * 4);
  unsigned*       bsum    = (unsigned*)alloc((size_t)SCB * 4);
  unsigned*       boff    = (unsigned*)alloc((size_t)SCB * 4);

  const int tb = 256;
  const int nb = (N_ + SCB - 1) / SCB;
  hipMemsetAsync(fill, 0, (size_t)N_ * 4, stream);
  k_encode<<<(N_ * 32 + tb - 1) / tb, tb, 0, stream>>>(x, Wn, bn, ln_w, ln_b, hA, pkA0, pkA1, N_, 5);
  k_fold<<<(L_ * H + 63) / 64, 64, 0, stream>>>(We, be, le_w, le_b, W2, b2, L_);
  k_hist<<<(E_ + tb - 1) / tb, tb, 0, stream>>>(dst, fill, E_);
  k_scan1<<<nb, SCB, 0, stream>>>(fill, row_ptr, bsum, N_);
  k_scan2<<<1, SCB, 0, stream>>>(bsum, boff, row_ptr + N_, nb);
  k_scan3<<<(N_ + tb - 1) / tb, tb, 0, stream>>>(row_ptr, boff, fill, N_);
  k_scatter<<<(E_ + tb - 1) / tb, tb, 0, stream>>>(src, dst, edge_attr, fill, recs, E_);

  float* hc = hA;  float* hn = hB;
  unsigned short* pc0 = pkA0; unsigned short* pc1 = pkA1;
  unsigned short* pn0 = pkB0; unsigned short* pn1 = pkB1;
  const int pgrid = (N_ * 16 + tb - 1) / tb;
  for (int l = 0; l < L_; ++l) {
    bool last = (l == L_ - 1);
    const float* w0b = W2 + l * 2 * H;
    const float* w1b = W2 + l * 2 * H + H;
    const float* bbb = b2 + l * H;
    k_pass<<<pgrid, tb, 0, stream>>>(pc0, row_ptr, (const unsigned long long*)recs,
                                     w0b, w1b, bbb, agg, N_);
    k_pass<<<pgrid, tb, 0, stream>>>(pc1, row_ptr, (const unsigned long long*)recs,
                                     w0b + 16, w1b + 16, bbb + 16, agg + 16, N_);
    k_update<<<(N_ * 32 + tb - 1) / tb, tb, 0, stream>>>(
        hc, agg, lu_w + (size_t)l * 2 * H * H, lu_b + (size_t)l * H,
        last ? nullptr : ln_w + (size_t)(l + 1) * H * H,
        last ? nullptr : ln_b + (size_t)(l + 1) * H,
        hn, last ? nullptr : pn0, last ? nullptr : pn1, N_);
    float* tf = hc; hc = hn; hn = tf;
    unsigned short* t0 = pc0; pc0 = pn0; pn0 = t0;
    unsigned short* t1 = pc1; pc1 = pn1; pn1 = t1;
  }
  k_cls<<<(N_ * 32 + tb - 1) / tb, tb, 0, stream>>>(hc, c1w, c1b, c2w, c2b, (float*)d_out, N_);
}

// Round 7
// 2780.292 us; speedup vs baseline: 1.5090x; 1.5090x over previous
//
#include <hip/hip_runtime.h>
#include <hip/hip_bf16.h>
#include <math.h>

#define H 32
#define SCB 1024

__device__ __forceinline__ unsigned f2bf(float f) {  // f32 -> bf16 bits, RNE
  unsigned u = __float_as_uint(f);
  return (u + 0x7fffu + ((u >> 16) & 1u)) >> 16;
}
__device__ __forceinline__ float bflo(unsigned p) { return __uint_as_float(p << 16); }
__device__ __forceinline__ float bfhi(unsigned p) { return __uint_as_float(p & 0xffff0000u); }

// h = x@Wn+bn ; pk[n][c] = {bf16(h) | bf16(h@lnw0+lnb0 - h)<<16}
__global__ void k_encode(const float* __restrict__ x, const float* __restrict__ Wn,
                         const float* __restrict__ bn, const float* __restrict__ lnw0,
                         const float* __restrict__ lnb0, float* __restrict__ h,
                         unsigned* __restrict__ pk, int n, int fnode) {
  __shared__ float sw[H * H];
  int tid = threadIdx.x;
  for (int i = tid; i < H * H; i += blockDim.x) sw[i] = lnw0[i];
  __syncthreads();
  int gid = blockIdx.x * blockDim.x + tid;
  int node = gid >> 5, c = gid & 31;
  if (node >= n) return;
  float acc = bn[c];
  for (int k = 0; k < fnode; ++k)
    acc = fmaf(x[node * fnode + k], Wn[k * H + c], acc);
  h[node * H + c] = acc;
  float t = lnb0[c];
#pragma unroll
  for (int k = 0; k < H; ++k)
    t = fmaf(__shfl(acc, k, 32), sw[k * H + c], t);
  pk[node * H + c] = f2bf(acc) | (f2bf(t - acc) << 16);
}

// W2[l] = We @ le_w[l]  ([2,H]) ; b2[l] = be @ le_w[l] + le_b[l]
__global__ void k_fold(const float* __restrict__ We, const float* __restrict__ be,
                       const float* __restrict__ lew, const float* __restrict__ leb,
                       float* __restrict__ W2, float* __restrict__ b2, int L) {
  int gid = blockIdx.x * blockDim.x + threadIdx.x;
  if (gid >= L * H) return;
  int l = gid >> 5, c = gid & 31;
  const float* lw = lew + (size_t)l * H * H;
  float a0 = 0.f, a1 = 0.f, bb = leb[l * H + c];
  for (int j = 0; j < H; ++j) {
    float w = lw[j * H + c];
    a0 = fmaf(We[j], w, a0);
    a1 = fmaf(We[H + j], w, a1);
    bb = fmaf(be[j], w, bb);
  }
  W2[l * 2 * H + c] = a0;
  W2[l * 2 * H + H + c] = a1;
  b2[l * H + c] = bb;
}

__global__ void k_hist(const int* __restrict__ dst, unsigned* __restrict__ cnt, int e) {
  int i = blockIdx.x * blockDim.x + threadIdx.x;
  if (i < e) atomicAdd(&cnt[dst[i]], 1u);
}

// two-level scan: per-block exclusive + block sums
__global__ void k_scan1(const unsigned* __restrict__ cnt, unsigned* __restrict__ out,
                        unsigned* __restrict__ bsum, int n) {
  __shared__ unsigned s[SCB];
  int i = blockIdx.x * SCB + threadIdx.x;
  unsigned v = (i < n) ? cnt[i] : 0u;
  s[threadIdx.x] = v;
  __syncthreads();
  for (int off = 1; off < SCB; off <<= 1) {
    unsigned u = (threadIdx.x >= off) ? s[threadIdx.x - off] : 0u;
    __syncthreads();
    s[threadIdx.x] += u;
    __syncthreads();
  }
  if (i < n) out[i] = s[threadIdx.x] - v;
  if (threadIdx.x == SCB - 1) bsum[blockIdx.x] = s[SCB - 1];
}

__global__ void k_scan2(const unsigned* __restrict__ bsum, unsigned* __restrict__ boff,
                        unsigned* __restrict__ total_out, int nb) {
  __shared__ unsigned s[SCB];
  unsigned v = ((int)threadIdx.x < nb) ? bsum[threadIdx.x] : 0u;
  s[threadIdx.x] = v;
  __syncthreads();
  for (int off = 1; off < SCB; off <<= 1) {
    unsigned u = (threadIdx.x >= off) ? s[threadIdx.x - off] : 0u;
    __syncthreads();
    s[threadIdx.x] += u;
    __syncthreads();
  }
  if ((int)threadIdx.x < nb) boff[threadIdx.x] = s[threadIdx.x] - v;
  if (threadIdx.x == SCB - 1) *total_out = s[SCB - 1];
}

__global__ void k_scan3(unsigned* __restrict__ row_ptr, const unsigned* __restrict__ boff,
                        unsigned* __restrict__ fill, int n) {
  int i = blockIdx.x * blockDim.x + threadIdx.x;
  if (i >= n) return;
  unsigned v = row_ptr[i] + boff[i >> 10];
  row_ptr[i] = v;
  fill[i] = v;
}

// rec = {src, bf16(attr0) | bf16(attr1)<<16}
__global__ void k_scatter(const int* __restrict__ src, const int* __restrict__ dst,
                          const float* __restrict__ ea, unsigned* __restrict__ fill,
                          uint2* __restrict__ recs, int e) {
  int i = blockIdx.x * blockDim.x + threadIdx.x;
  if (i >= e) return;
  int d = dst[i];
  unsigned pos = atomicAdd(&fill[d], 1u);
  float2 a = ((const float2*)ea)[i];
  recs[pos] = make_uint2((unsigned)src[i], f2bf(a.x) | (f2bf(a.y) << 16));
}

// one WAVE (64 lanes) per dst node: 2 parity groups x 32 channels.
// 16 edges in flight per round (8 per parity, software-pipelined recs).
__global__ void __launch_bounds__(256) k_layer(
    const float* __restrict__ h, const unsigned* __restrict__ pk,
    const unsigned* __restrict__ row_ptr, const uint2* __restrict__ recs,
    const float* __restrict__ W2l, const float* __restrict__ b2l,
    const float* __restrict__ luw, const float* __restrict__ lub,
    const float* __restrict__ lnw_next, const float* __restrict__ lnb_next,
    float* __restrict__ hout, unsigned* __restrict__ pk_out, int n) {
  __shared__ float sw[2 * H * H];   // lu_w (8 KB)
  __shared__ float swn[H * H];      // next ln_w (4 KB)
  int tid = threadIdx.x;
  for (int i = tid; i < 2 * H * H; i += 256) sw[i] = luw[i];
  if (lnw_next)
    for (int i = tid; i < H * H; i += 256) swn[i] = lnw_next[i];
  __syncthreads();
  int lane = tid & 63;
  int node = blockIdx.x * 4 + (tid >> 6);
  int p = lane >> 5, c = lane & 31;
  if (node >= n) return;
  float w0 = W2l[c], w1 = W2l[H + c], bb = b2l[c];
  unsigned s0 = row_ptr[node], s1 = row_ptr[node + 1];
  float acc = 0.f;
  if (s0 < s1) {
    uint2 r0[8]; float sc0[8];
    unsigned base = s0 + (unsigned)p * 8;
#pragma unroll
    for (int j = 0; j < 8; ++j) {
      unsigned idx = base + (unsigned)j;
      sc0[j] = (idx < s1) ? 1.f : 0.f;
      r0[j] = recs[(idx < s1) ? idx : s0];
    }
    for (unsigned i = s0; i < s1; i += 16) {
      unsigned pv[8];
#pragma unroll
      for (int j = 0; j < 8; ++j) pv[j] = pk[r0[j].x * H + c];
      bool more = (i + 16) < s1;
      uint2 r1[8]; float sc1[8];
      if (more) {
        unsigned nb = i + 16 + (unsigned)p * 8;
#pragma unroll
        for (int j = 0; j < 8; ++j) {
          unsigned idx = nb + (unsigned)j;
          sc1[j] = (idx < s1) ? 1.f : 0.f;
          r1[j] = recs[(idx < s1) ? idx : s0];
        }
      }
#pragma unroll
      for (int j = 0; j < 8; ++j) {
        float ee = fmaf(bflo(r0[j].y), w0, fmaf(bfhi(r0[j].y), w1, bb));
        acc = fmaf(sc0[j], fmaf(ee, bfhi(pv[j]), bflo(pv[j])), acc);
      }
      if (more) {
#pragma unroll
        for (int j = 0; j < 8; ++j) { r0[j] = r1[j]; sc0[j] = sc1[j]; }
      }
    }
  }
  acc += __shfl_xor(acc, 32, 64);   // fold parity halves: full msg sum, all lanes
  float hc = h[node * H + c];
  // split-k node update: half p sums k = p*16 .. p*16+15
  float o = (p == 0) ? lub[c] : 0.f;
#pragma unroll
  for (int kk = 0; kk < 16; ++kk) {
    int k = p * 16 + kk;
    o = fmaf(__shfl(hc, k, 64), sw[k * H + c], o);
    o = fmaf(__shfl(acc, k, 64), sw[(H + k) * H + c], o);
  }
  o += __shfl_xor(o, 32, 64);
  o = fmaxf(o, 0.f);
  if (p == 0) hout[node * H + c] = o;
  if (pk_out) {
    float t = (p == 0) ? lnb_next[c] : 0.f;
#pragma unroll
    for (int kk = 0; kk < 16; ++kk) {
      int k = p * 16 + kk;
      t = fmaf(__shfl(o, k, 64), swn[k * H + c], t);
    }
    t += __shfl_xor(t, 32, 64);
    if (p == 0) pk_out[node * H + c] = f2bf(o) | (f2bf(t - o) << 16);
  }
}

// classifier: sigmoid(relu(h@c1+b1)@c2 + b2)
__global__ void k_cls(const float* __restrict__ h, const float* __restrict__ c1w,
                      const float* __restrict__ c1b, const float* __restrict__ c2w,
                      const float* __restrict__ c2b, float* __restrict__ out, int n) {
  __shared__ float sw[H * H];
  int tid = threadIdx.x;
  for (int i = tid; i < H * H; i += blockDim.x) sw[i] = c1w[i];
  __syncthreads();
  int gid = blockIdx.x * blockDim.x + tid;
  int node = gid >> 5, c = gid & 31;
  if (node >= n) return;
  float hv = h[node * H + c];
  float z = c1b[c];
#pragma unroll
  for (int k = 0; k < H; ++k)
    z = fmaf(__shfl(hv, k, 32), sw[k * H + c], z);
  z = fmaxf(z, 0.f);
  float r = z * c2w[c];
#pragma unroll
  for (int m = 16; m >= 1; m >>= 1)
    r += __shfl_xor(r, m, 32);
  if (c == 0) out[node] = 1.f / (1.f + expf(-(r + c2b[0])));
}

extern "C" void kernel_launch(void* const* d_in, const int* in_sizes, int n_in,
                              void* d_out, int out_size, void* d_ws, size_t ws_size,
                              hipStream_t stream) {
  const float* x         = (const float*)d_in[0];
  const float* edge_attr = (const float*)d_in[1];
  const int*   edge_index= (const int*)d_in[2];
  const float* Wn        = (const float*)d_in[3];
  const float* bn        = (const float*)d_in[4];
  const float* We        = (const float*)d_in[5];
  const float* be        = (const float*)d_in[6];
  const float* ln_w      = (const float*)d_in[7];
  const float* ln_b      = (const float*)d_in[8];
  const float* le_w      = (const float*)d_in[9];
  const float* le_b      = (const float*)d_in[10];
  const float* lu_w      = (const float*)d_in[11];
  const float* lu_b      = (const float*)d_in[12];
  const float* c1w       = (const float*)d_in[13];
  const float* c1b       = (const float*)d_in[14];
  const float* c2w       = (const float*)d_in[15];
  const float* c2b       = (const float*)d_in[16];

  const int N_ = in_sizes[0] / 5;
  const int E_ = in_sizes[1] / 2;
  const int L_ = in_sizes[7] / (H * H);
  const int* src = edge_index;
  const int* dst = edge_index + E_;

  char* ws = (char*)d_ws;
  size_t off = 0;
  auto alloc = [&](size_t bytes) -> void* {
    void* p = ws + off;
    off = (off + bytes + 255) & ~(size_t)255;
    return p;
  };
  float*    hA      = (float*)alloc((size_t)N_ * H * 4);
  float*    hB      = (float*)alloc((size_t)N_ * H * 4);
  unsigned* pkA     = (unsigned*)alloc((size_t)N_ * H * 4);
  unsigned* pkB     = (unsigned*)alloc((size_t)N_ * H * 4);
  unsigned* row_ptr = (unsigned*)alloc((size_t)(N_ + 1) * 4);
  unsigned* fill    = (unsigned*)alloc((size_t)N_ * 4);
  uint2*    recs    = (uint2*)alloc((size_t)E_ * 8);
  float*    W2      = (float*)alloc((size_t)L_ * 2 * H * 4);
  float*    b2      = (float*)alloc((size_t)L_ * H * 4);
  unsigned* bsum    = (unsigned*)alloc((size_t)SCB * 4);
  unsigned* boff    = (unsigned*)alloc((size_t)SCB * 4);

  const int tb = 256;
  const int nb = (N_ + SCB - 1) / SCB;
  hipMemsetAsync(fill, 0, (size_t)N_ * 4, stream);
  k_encode<<<(N_ * 32 + tb - 1) / tb, tb, 0, stream>>>(x, Wn, bn, ln_w, ln_b, hA, pkA, N_, 5);
  k_fold<<<(L_ * H + 63) / 64, 64, 0, stream>>>(We, be, le_w, le_b, W2, b2, L_);
  k_hist<<<(E_ + tb - 1) / tb, tb, 0, stream>>>(dst, fill, E_);
  k_scan1<<<nb, SCB, 0, stream>>>(fill, row_ptr, bsum, N_);
  k_scan2<<<1, SCB, 0, stream>>>(bsum, boff, row_ptr + N_, nb);
  k_scan3<<<(N_ + tb - 1) / tb, tb, 0, stream>>>(row_ptr, boff, fill, N_);
  k_scatter<<<(E_ + tb - 1) / tb, tb, 0, stream>>>(src, dst, edge_attr, fill, recs, E_);

  float* hc = hA;  float* hn = hB;
  unsigned* pc = pkA; unsigned* pn = pkB;
  for (int l = 0; l < L_; ++l) {
    bool last = (l == L_ - 1);
    k_layer<<<(N_ + 3) / 4, 256, 0, stream>>>(
        hc, pc, row_ptr, recs, W2 + l * 2 * H, b2 + l * H,
        lu_w + (size_t)l * 2 * H * H, lu_b + (size_t)l * H,
        last ? nullptr : ln_w + (size_t)(l + 1) * H * H,
        last ? nullptr : ln_b + (size_t)(l + 1) * H,
        hn, last ? nullptr : pn, N_);
    float* tf = hc; hc = hn; hn = tf;
    unsigned* tp = pc; pc = pn; pn = tp;
  }
  k_cls<<<(N_ * 32 + tb - 1) / tb, tb, 0, stream>>>(hc, c1w, c1b, c2w, c2b, (float*)d_out, N_);
}

// Round 8
// 2699.257 us; speedup vs baseline: 1.5543x; 1.0300x over previous
//
#include <hip/hip_runtime.h>
#include <hip/hip_bf16.h>
#include <hip/hip_fp8.h>
#include <math.h>

#define H 32
#define SCB 1024

__device__ __forceinline__ unsigned f2bf(float f) {  // f32 -> bf16 bits, RNE
  unsigned u = __float_as_uint(f);
  return (u + 0x7fffu + ((u >> 16) & 1u)) >> 16;
}
__device__ __forceinline__ float bflo(unsigned p) { return __uint_as_float(p << 16); }
__device__ __forceinline__ float bfhi(unsigned p) { return __uint_as_float(p & 0xffff0000u); }

// f32 -> OCP e4m3fn byte (RNE, saturating)
__device__ __forceinline__ unsigned f2q(float f) {
  __hip_fp8_e4m3 q(f);
  return (unsigned)q.__x;
}
// manual e4m3fn -> f32 (fallback only)
__device__ __forceinline__ float q2f(unsigned b) {
  unsigned s = (b >> 7) & 1u, e = (b >> 3) & 15u, m = b & 7u;
  float vn = __uint_as_float((s << 31) | ((e + 120u) << 23) | (m << 20));
  float vs = __uint_as_float((s << 31) | 0x3f800000u) * ((float)(int)m * (1.0f / 512.0f));
  return (e == 0u) ? vs : vn;
}

// decode channel pair (x,u) from a dword of packed fp8 {x0,u0,x1,u1}
template <bool HI>
__device__ __forceinline__ void cvt2(unsigned dw, float& x, float& u) {
#if __has_builtin(__builtin_amdgcn_cvt_pk_f32_fp8)
  typedef float f32x2 __attribute__((ext_vector_type(2)));
  f32x2 v = __builtin_amdgcn_cvt_pk_f32_fp8((int)dw, HI);
  x = v[0]; u = v[1];
#else
  unsigned b = HI ? (dw >> 16) : dw;
  x = q2f(b & 255u); u = q2f((b >> 8) & 255u);
#endif
}

// h = x@Wn+bn ; pk[n][16 dwords]: dword d = {x(2d),u(2d),x(2d+1),u(2d+1)} fp8
__global__ void k_encode(const float* __restrict__ x, const float* __restrict__ Wn,
                         const float* __restrict__ bn, const float* __restrict__ lnw0,
                         const float* __restrict__ lnb0, float* __restrict__ h,
                         unsigned* __restrict__ pk, int n, int fnode) {
  __shared__ float sw[H * H];
  int tid = threadIdx.x;
  for (int i = tid; i < H * H; i += blockDim.x) sw[i] = lnw0[i];
  __syncthreads();
  int gid = blockIdx.x * blockDim.x + tid;
  int node = gid >> 5, c = gid & 31;
  if (node >= n) return;
  float acc = bn[c];
  for (int k = 0; k < fnode; ++k)
    acc = fmaf(x[node * fnode + k], Wn[k * H + c], acc);
  h[node * H + c] = acc;
  float t = lnb0[c];
#pragma unroll
  for (int k = 0; k < H; ++k)
    t = fmaf(__shfl(acc, k, 32), sw[k * H + c], t);
  unsigned w = f2q(acc) | (f2q(t - acc) << 8);
  unsigned dw = w | (__shfl_xor(w, 1, 32) << 16);
  if (!(c & 1)) pk[node * 16 + (c >> 1)] = dw;
}

// W2[l] = We @ le_w[l]  ([2,H]) ; b2[l] = be @ le_w[l] + le_b[l]
__global__ void k_fold(const float* __restrict__ We, const float* __restrict__ be,
                       const float* __restrict__ lew, const float* __restrict__ leb,
                       float* __restrict__ W2, float* __restrict__ b2, int L) {
  int gid = blockIdx.x * blockDim.x + threadIdx.x;
  if (gid >= L * H) return;
  int l = gid >> 5, c = gid & 31;
  const float* lw = lew + (size_t)l * H * H;
  float a0 = 0.f, a1 = 0.f, bb = leb[l * H + c];
  for (int j = 0; j < H; ++j) {
    float w = lw[j * H + c];
    a0 = fmaf(We[j], w, a0);
    a1 = fmaf(We[H + j], w, a1);
    bb = fmaf(be[j], w, bb);
  }
  W2[l * 2 * H + c] = a0;
  W2[l * 2 * H + H + c] = a1;
  b2[l * H + c] = bb;
}

__global__ void k_hist(const int* __restrict__ dst, unsigned* __restrict__ cnt, int e) {
  int i = blockIdx.x * blockDim.x + threadIdx.x;
  if (i < e) atomicAdd(&cnt[dst[i]], 1u);
}

__global__ void k_scan1(const unsigned* __restrict__ cnt, unsigned* __restrict__ out,
                        unsigned* __restrict__ bsum, int n) {
  __shared__ unsigned s[SCB];
  int i = blockIdx.x * SCB + threadIdx.x;
  unsigned v = (i < n) ? cnt[i] : 0u;
  s[threadIdx.x] = v;
  __syncthreads();
  for (int off = 1; off < SCB; off <<= 1) {
    unsigned u = (threadIdx.x >= off) ? s[threadIdx.x - off] : 0u;
    __syncthreads();
    s[threadIdx.x] += u;
    __syncthreads();
  }
  if (i < n) out[i] = s[threadIdx.x] - v;
  if (threadIdx.x == SCB - 1) bsum[blockIdx.x] = s[SCB - 1];
}

__global__ void k_scan2(const unsigned* __restrict__ bsum, unsigned* __restrict__ boff,
                        unsigned* __restrict__ total_out, int nb) {
  __shared__ unsigned s[SCB];
  unsigned v = ((int)threadIdx.x < nb) ? bsum[threadIdx.x] : 0u;
  s[threadIdx.x] = v;
  __syncthreads();
  for (int off = 1; off < SCB; off <<= 1) {
    unsigned u = (threadIdx.x >= off) ? s[threadIdx.x - off] : 0u;
    __syncthreads();
    s[threadIdx.x] += u;
    __syncthreads();
  }
  if ((int)threadIdx.x < nb) boff[threadIdx.x] = s[threadIdx.x] - v;
  if (threadIdx.x == SCB - 1) *total_out = s[SCB - 1];
}

__global__ void k_scan3(unsigned* __restrict__ row_ptr, const unsigned* __restrict__ boff,
                        unsigned* __restrict__ fill, int n) {
  int i = blockIdx.x * blockDim.x + threadIdx.x;
  if (i >= n) return;
  unsigned v = row_ptr[i] + boff[i >> 10];
  row_ptr[i] = v;
  fill[i] = v;
}

// rec = {src, bf16(attr0) | bf16(attr1)<<16}
__global__ void k_scatter(const int* __restrict__ src, const int* __restrict__ dst,
                          const float* __restrict__ ea, unsigned* __restrict__ fill,
                          uint2* __restrict__ recs, int e) {
  int i = blockIdx.x * blockDim.x + threadIdx.x;
  if (i >= e) return;
  int d = dst[i];
  unsigned pos = atomicAdd(&fill[d], 1u);
  float2 a = ((const float2*)ea)[i];
  recs[pos] = make_uint2((unsigned)src[i], f2bf(a.x) | (f2bf(a.y) << 16));
}

// one wave per dst node. Per round: 16 edges per gather instruction
// (4 lanes x dwordx4 per 64B fp8 row). Lane handles 8 channels of 1 edge.
__global__ void __launch_bounds__(256) k_layer(
    const float* __restrict__ h, const unsigned* __restrict__ pk,
    const unsigned* __restrict__ row_ptr, const uint2* __restrict__ recs,
    const float* __restrict__ W2l, const float* __restrict__ b2l,
    const float* __restrict__ luw, const float* __restrict__ lub,
    const float* __restrict__ lnw_next, const float* __restrict__ lnb_next,
    float* __restrict__ hout, unsigned* __restrict__ pk_out, int n) {
  __shared__ float sw[2 * H * H];   // lu_w (8 KB)
  __shared__ float swn[H * H];      // next ln_w (4 KB)
  __shared__ float aggS[4][H];
  int tid = threadIdx.x;
  for (int i = tid; i < 2 * H * H; i += 256) sw[i] = luw[i];
  if (lnw_next)
    for (int i = tid; i < H * H; i += 256) swn[i] = lnw_next[i];
  __syncthreads();
  int wid = tid >> 6, lane = tid & 63;
  int node = blockIdx.x * 4 + wid;
  if (node >= n) return;
  int sub = lane & 3;          // which 16B quarter of the 64B row
  unsigned eoff = (unsigned)(lane >> 2);  // which of 16 edges this round
  int c = lane & 31, p = lane >> 5;
  // per-lane folded edge-MLP weights for its 8 channels
  float w0v[8], w1v[8], bbv[8];
#pragma unroll
  for (int j = 0; j < 8; ++j) {
    int ch = sub * 8 + j;
    w0v[j] = W2l[ch]; w1v[j] = W2l[H + ch]; bbv[j] = b2l[ch];
  }
  unsigned s0 = row_ptr[node], s1 = row_ptr[node + 1];
  float acc[8] = {0.f, 0.f, 0.f, 0.f, 0.f, 0.f, 0.f, 0.f};
  const uint4* pk4 = (const uint4*)pk;
  if (s0 < s1) {
    unsigned idx = s0 + eoff;
    float v0 = (idx < s1) ? 1.f : 0.f;
    uint2 r0 = recs[(idx < s1) ? idx : s0];
    for (unsigned i = s0; i < s1; i += 16) {
      uint4 pv = pk4[(size_t)r0.x * 4 + sub];
      bool more = (i + 16) < s1;
      uint2 r1 = r0; float v1 = 0.f;
      if (more) {
        unsigned id2 = i + 16 + eoff;
        v1 = (id2 < s1) ? 1.f : 0.f;
        r1 = recs[(id2 < s1) ? id2 : s0];
      }
      float a0 = bflo(r0.y), a1 = bfhi(r0.y);
      unsigned dws[4] = {pv.x, pv.y, pv.z, pv.w};
#pragma unroll
      for (int d = 0; d < 4; ++d) {
        float x0, u0, x1, u1;
        cvt2<false>(dws[d], x0, u0);
        cvt2<true>(dws[d], x1, u1);
        float e0 = fmaf(a0, w0v[2 * d], fmaf(a1, w1v[2 * d], bbv[2 * d]));
        float e1 = fmaf(a0, w0v[2 * d + 1], fmaf(a1, w1v[2 * d + 1], bbv[2 * d + 1]));
        acc[2 * d]     = fmaf(v0, fmaf(e0, u0, x0), acc[2 * d]);
        acc[2 * d + 1] = fmaf(v0, fmaf(e1, u1, x1), acc[2 * d + 1]);
      }
      r0 = r1; v0 = v1;
    }
  }
  // reduce the 16 lane-quads holding the same channel block
#pragma unroll
  for (int j = 0; j < 8; ++j) {
    acc[j] += __shfl_xor(acc[j], 4, 64);
    acc[j] += __shfl_xor(acc[j], 8, 64);
    acc[j] += __shfl_xor(acc[j], 16, 64);
    acc[j] += __shfl_xor(acc[j], 32, 64);
  }
  if (lane < 4) {
#pragma unroll
    for (int j = 0; j < 8; ++j) aggS[wid][lane * 8 + j] = acc[j];
  }
  asm volatile("s_waitcnt lgkmcnt(0)" ::: "memory");
  float msum = aggS[wid][c];
  float hc = h[node * H + c];
  // split-k node update: half p sums k = p*16 .. p*16+15
  float o = (p == 0) ? lub[c] : 0.f;
#pragma unroll
  for (int kk = 0; kk < 16; ++kk) {
    int k = p * 16 + kk;
    o = fmaf(__shfl(hc, k, 64), sw[k * H + c], o);
    o = fmaf(__shfl(msum, k, 64), sw[(H + k) * H + c], o);
  }
  o += __shfl_xor(o, 32, 64);
  o = fmaxf(o, 0.f);
  if (p == 0) hout[node * H + c] = o;
  if (pk_out) {
    float t = (p == 0) ? lnb_next[c] : 0.f;
#pragma unroll
    for (int kk = 0; kk < 16; ++kk) {
      int k = p * 16 + kk;
      t = fmaf(__shfl(o, k, 64), swn[k * H + c], t);
    }
    t += __shfl_xor(t, 32, 64);
    unsigned w = f2q(o) | (f2q(t - o) << 8);
    unsigned dw = w | (__shfl_xor(w, 1, 64) << 16);
    if (p == 0 && !(c & 1)) pk_out[node * 16 + (c >> 1)] = dw;
  }
}

// classifier: sigmoid(relu(h@c1+b1)@c2 + b2)
__global__ void k_cls(const float* __restrict__ h, const float* __restrict__ c1w,
                      const float* __restrict__ c1b, const float* __restrict__ c2w,
                      const float* __restrict__ c2b, float* __restrict__ out, int n) {
  __shared__ float sw[H * H];
  int tid = threadIdx.x;
  for (int i = tid; i < H * H; i += blockDim.x) sw[i] = c1w[i];
  __syncthreads();
  int gid = blockIdx.x * blockDim.x + tid;
  int node = gid >> 5, c = gid & 31;
  if (node >= n) return;
  float hv = h[node * H + c];
  float z = c1b[c];
#pragma unroll
  for (int k = 0; k < H; ++k)
    z = fmaf(__shfl(hv, k, 32), sw[k * H + c], z);
  z = fmaxf(z, 0.f);
  float r = z * c2w[c];
#pragma unroll
  for (int m = 16; m >= 1; m >>= 1)
    r += __shfl_xor(r, m, 32);
  if (c == 0) out[node] = 1.f / (1.f + expf(-(r + c2b[0])));
}

extern "C" void kernel_launch(void* const* d_in, const int* in_sizes, int n_in,
                              void* d_out, int out_size, void* d_ws, size_t ws_size,
                              hipStream_t stream) {
  const float* x         = (const float*)d_in[0];
  const float* edge_attr = (const float*)d_in[1];
  const int*   edge_index= (const int*)d_in[2];
  const float* Wn        = (const float*)d_in[3];
  const float* bn        = (const float*)d_in[4];
  const float* We        = (const float*)d_in[5];
  const float* be        = (const float*)d_in[6];
  const float* ln_w      = (const float*)d_in[7];
  const float* ln_b      = (const float*)d_in[8];
  const float* le_w      = (const float*)d_in[9];
  const float* le_b      = (const float*)d_in[10];
  const float* lu_w      = (const float*)d_in[11];
  const float* lu_b      = (const float*)d_in[12];
  const float* c1w       = (const float*)d_in[13];
  const float* c1b       = (const float*)d_in[14];
  const float* c2w       = (const float*)d_in[15];
  const float* c2b       = (const float*)d_in[16];

  const int N_ = in_sizes[0] / 5;
  const int E_ = in_sizes[1] / 2;
  const int L_ = in_sizes[7] / (H * H);
  const int* src = edge_index;
  const int* dst = edge_index + E_;

  char* ws = (char*)d_ws;
  size_t off = 0;
  auto alloc = [&](size_t bytes) -> void* {
    void* p = ws + off;
    off = (off + bytes + 255) & ~(size_t)255;
    return p;
  };
  float*    hA      = (float*)alloc((size_t)N_ * H * 4);
  float*    hB      = (float*)alloc((size_t)N_ * H * 4);
  unsigned* pkA     = (unsigned*)alloc((size_t)N_ * 16 * 4);
  unsigned* pkB     = (unsigned*)alloc((size_t)N_ * 16 * 4);
  unsigned* row_ptr = (unsigned*)alloc((size_t)(N_ + 1) * 4);
  unsigned* fill    = (unsigned*)alloc((size_t)N_ * 4);
  uint2*    recs    = (uint2*)alloc((size_t)E_ * 8);
  float*    W2      = (float*)alloc((size_t)L_ * 2 * H * 4);
  float*    b2      = (float*)alloc((size_t)L_ * H * 4);
  unsigned* bsum    = (unsigned*)alloc((size_t)SCB * 4);
  unsigned* boff    = (unsigned*)alloc((size_t)SCB * 4);

  const int tb = 256;
  const int nb = (N_ + SCB - 1) / SCB;
  hipMemsetAsync(fill, 0, (size_t)N_ * 4, stream);
  k_encode<<<(N_ * 32 + tb - 1) / tb, tb, 0, stream>>>(x, Wn, bn, ln_w, ln_b, hA, pkA, N_, 5);
  k_fold<<<(L_ * H + 63) / 64, 64, 0, stream>>>(We, be, le_w, le_b, W2, b2, L_);
  k_hist<<<(E_ + tb - 1) / tb, tb, 0, stream>>>(dst, fill, E_);
  k_scan1<<<nb, SCB, 0, stream>>>(fill, row_ptr, bsum, N_);
  k_scan2<<<1, SCB, 0, stream>>>(bsum, boff, row_ptr + N_, nb);
  k_scan3<<<(N_ + tb - 1) / tb, tb, 0, stream>>>(row_ptr, boff, fill, N_);
  k_scatter<<<(E_ + tb - 1) / tb, tb, 0, stream>>>(src, dst, edge_attr, fill, recs, E_);

  float* hc = hA;  float* hn = hB;
  unsigned* pc = pkA; unsigned* pn = pkB;
  for (int l = 0; l < L_; ++l) {
    bool last = (l == L_ - 1);
    k_layer<<<(N_ + 3) / 4, 256, 0, stream>>>(
        hc, pc, row_ptr, recs, W2 + l * 2 * H, b2 + l * H,
        lu_w + (size_t)l * 2 * H * H, lu_b + (size_t)l * H,
        last ? nullptr : ln_w + (size_t)(l + 1) * H * H,
        last ? nullptr : ln_b + (size_t)(l + 1) * H,
        hn, last ? nullptr : pn, N_);
    float* tf = hc; hc = hn; hn = tf;
    unsigned* tp = pc; pc = pn; pn = tp;
  }
  k_cls<<<(N_ * 32 + tb - 1) / tb, tb, 0, stream>>>(hc, c1w, c1b, c2w, c2b, (float*)d_out, N_);
}

// Round 10
// 2076.204 us; speedup vs baseline: 2.0207x; 1.3001x over previous
//
#include <hip/hip_runtime.h>
#include <hip/hip_bf16.h>
#include <hip/hip_fp8.h>
#include <math.h>

#define H 32
#define SCB 1024

__device__ __forceinline__ unsigned f2bf(float f) {  // f32 -> bf16 bits, RNE
  unsigned u = __float_as_uint(f);
  return (u + 0x7fffu + ((u >> 16) & 1u)) >> 16;
}
__device__ __forceinline__ float bflo(unsigned p) { return __uint_as_float(p << 16); }
__device__ __forceinline__ float bfhi(unsigned p) { return __uint_as_float(p & 0xffff0000u); }

// f32 -> OCP e4m3fn byte (RNE, saturating) — the PROVEN encode path (r7)
__device__ __forceinline__ unsigned f2q(float f) {
  __hip_fp8_e4m3 q(f);
  return (unsigned)q.__x;
}
// manual e4m3fn -> f32 (fallback only)
__device__ __forceinline__ float q2f(unsigned b) {
  unsigned s = (b >> 7) & 1u, e = (b >> 3) & 15u, m = b & 7u;
  float vn = __uint_as_float((s << 31) | ((e + 120u) << 23) | (m << 20));
  float vs = __uint_as_float((s << 31) | 0x3f800000u) * ((float)(int)m * (1.0f / 512.0f));
  return (e == 0u) ? vs : vn;
}

// decode channel pair (x,u) from a dword of packed fp8 {x0,u0,x1,u1} (proven r7)
template <bool HI>
__device__ __forceinline__ void cvt2(unsigned dw, float& x, float& u) {
#if __has_builtin(__builtin_amdgcn_cvt_pk_f32_fp8)
  typedef float f32x2 __attribute__((ext_vector_type(2)));
  f32x2 v = __builtin_amdgcn_cvt_pk_f32_fp8((int)dw, HI);
  x = v[0]; u = v[1];
#else
  unsigned b = HI ? (dw >> 16) : dw;
  x = q2f(b & 255u); u = q2f((b >> 8) & 255u);
#endif
}

// pack {fp8(x0),fp8(u0),fp8(x1),fp8(u1)} into one dword — f2q only (r9 builtin reverted)
__device__ __forceinline__ unsigned pack4(float x0, float u0, float x1, float u1) {
  return f2q(x0) | (f2q(u0) << 8) | (f2q(x1) << 16) | (f2q(u1) << 24);
}

// h = x@Wn+bn ; pk[n][16 dwords]: dword d = {x(2d),u(2d),x(2d+1),u(2d+1)} fp8
__global__ void k_encode(const float* __restrict__ x, const float* __restrict__ Wn,
                         const float* __restrict__ bn, const float* __restrict__ lnw0,
                         const float* __restrict__ lnb0, float* __restrict__ h,
                         unsigned* __restrict__ pk, int n, int fnode) {
  __shared__ float sw[H * H];
  int tid = threadIdx.x;
  for (int i = tid; i < H * H; i += blockDim.x) sw[i] = lnw0[i];
  __syncthreads();
  int gid = blockIdx.x * blockDim.x + tid;
  int node = gid >> 5, c = gid & 31;
  if (node >= n) return;
  float acc = bn[c];
  for (int k = 0; k < fnode; ++k)
    acc = fmaf(x[node * fnode + k], Wn[k * H + c], acc);
  h[node * H + c] = acc;
  float t = lnb0[c];
#pragma unroll
  for (int k = 0; k < H; ++k)
    t = fmaf(__shfl(acc, k, 32), sw[k * H + c], t);
  unsigned w = f2q(acc) | (f2q(t - acc) << 8);
  unsigned dw = w | (__shfl_xor(w, 1, 32) << 16);
  if (!(c & 1)) pk[node * 16 + (c >> 1)] = dw;
}

// W2[l] = We @ le_w[l]  ([2,H]) ; b2[l] = be @ le_w[l] + le_b[l]
__global__ void k_fold(const float* __restrict__ We, const float* __restrict__ be,
                       const float* __restrict__ lew, const float* __restrict__ leb,
                       float* __restrict__ W2, float* __restrict__ b2, int L) {
  int gid = blockIdx.x * blockDim.x + threadIdx.x;
  if (gid >= L * H) return;
  int l = gid >> 5, c = gid & 31;
  const float* lw = lew + (size_t)l * H * H;
  float a0 = 0.f, a1 = 0.f, bb = leb[l * H + c];
  for (int j = 0; j < H; ++j) {
    float w = lw[j * H + c];
    a0 = fmaf(We[j], w, a0);
    a1 = fmaf(We[H + j], w, a1);
    bb = fmaf(be[j], w, bb);
  }
  W2[l * 2 * H + c] = a0;
  W2[l * 2 * H + H + c] = a1;
  b2[l * H + c] = bb;
}

__global__ void k_hist(const int* __restrict__ dst, unsigned* __restrict__ cnt, int e) {
  int i = blockIdx.x * blockDim.x + threadIdx.x;
  if (i < e) atomicAdd(&cnt[dst[i]], 1u);
}

__global__ void k_scan1(const unsigned* __restrict__ cnt, unsigned* __restrict__ out,
                        unsigned* __restrict__ bsum, int n) {
  __shared__ unsigned s[SCB];
  int i = blockIdx.x * SCB + threadIdx.x;
  unsigned v = (i < n) ? cnt[i] : 0u;
  s[threadIdx.x] = v;
  __syncthreads();
  for (int off = 1; off < SCB; off <<= 1) {
    unsigned u = (threadIdx.x >= off) ? s[threadIdx.x - off] : 0u;
    __syncthreads();
    s[threadIdx.x] += u;
    __syncthreads();
  }
  if (i < n) out[i] = s[threadIdx.x] - v;
  if (threadIdx.x == SCB - 1) bsum[blockIdx.x] = s[SCB - 1];
}

__global__ void k_scan2(const unsigned* __restrict__ bsum, unsigned* __restrict__ boff,
                        unsigned* __restrict__ total_out, int nb) {
  __shared__ unsigned s[SCB];
  unsigned v = ((int)threadIdx.x < nb) ? bsum[threadIdx.x] : 0u;
  s[threadIdx.x] = v;
  __syncthreads();
  for (int off = 1; off < SCB; off <<= 1) {
    unsigned u = (threadIdx.x >= off) ? s[threadIdx.x - off] : 0u;
    __syncthreads();
    s[threadIdx.x] += u;
    __syncthreads();
  }
  if ((int)threadIdx.x < nb) boff[threadIdx.x] = s[threadIdx.x] - v;
  if (threadIdx.x == SCB - 1) *total_out = s[SCB - 1];
}

__global__ void k_scan3(unsigned* __restrict__ row_ptr, const unsigned* __restrict__ boff,
                        unsigned* __restrict__ fill, int n) {
  int i = blockIdx.x * blockDim.x + threadIdx.x;
  if (i >= n) return;
  unsigned v = row_ptr[i] + boff[i >> 10];
  row_ptr[i] = v;
  fill[i] = v;
}

// rec = {src, bf16(attr0) | bf16(attr1)<<16}
__global__ void k_scatter(const int* __restrict__ src, const int* __restrict__ dst,
                          const float* __restrict__ ea, unsigned* __restrict__ fill,
                          uint2* __restrict__ recs, int e) {
  int i = blockIdx.x * blockDim.x + threadIdx.x;
  if (i >= e) return;
  int d = dst[i];
  unsigned pos = atomicAdd(&fill[d], 1u);
  float2 a = ((const float2*)ea)[i];
  recs[pos] = make_uint2((unsigned)src[i], f2bf(a.x) | (f2bf(a.y) << 16));
}

__device__ __forceinline__ void edge_acc(float (&acc)[8], uint4 pv, uint2 rec, float v,
                                         const float (&w0v)[8], const float (&w1v)[8],
                                         const float (&bbv)[8]) {
  float a0 = bflo(rec.y), a1 = bfhi(rec.y);
  unsigned dws[4] = {pv.x, pv.y, pv.z, pv.w};
#pragma unroll
  for (int d = 0; d < 4; ++d) {
    float x0, u0, x1, u1;
    cvt2<false>(dws[d], x0, u0);
    cvt2<true>(dws[d], x1, u1);
    float e0 = fmaf(a0, w0v[2 * d], fmaf(a1, w1v[2 * d], bbv[2 * d]));
    float e1 = fmaf(a0, w0v[2 * d + 1], fmaf(a1, w1v[2 * d + 1], bbv[2 * d + 1]));
    acc[2 * d]     = fmaf(v, fmaf(e0, u0, x0), acc[2 * d]);
    acc[2 * d + 1] = fmaf(v, fmaf(e1, u1, x1), acc[2 * d + 1]);
  }
}

// gather-only: one wave = 2 interleaved dst nodes; 16 edges/gather-instr each;
// no LDS weights, no __syncthreads; writes f32 agg[node][32].
__global__ void __launch_bounds__(256) k_gather(
    const unsigned* __restrict__ pk, const unsigned* __restrict__ row_ptr,
    const uint2* __restrict__ recs, const float* __restrict__ W2l,
    const float* __restrict__ b2l, float* __restrict__ agg, int n, int e) {
  int tid = threadIdx.x;
  int lane = tid & 63;
  int gw = blockIdx.x * 4 + (tid >> 6);
  int n0 = gw * 2, n1 = n0 + 1;
  if (n0 >= n) return;
  int sub = lane & 3;
  unsigned eoff = (unsigned)(lane >> 2);
  float w0v[8], w1v[8], bbv[8];
#pragma unroll
  for (int j = 0; j < 8; ++j) {
    int ch = sub * 8 + j;
    w0v[j] = W2l[ch]; w1v[j] = W2l[H + ch]; bbv[j] = b2l[ch];
  }
  unsigned a0 = row_ptr[n0], a1 = row_ptr[n0 + 1];
  unsigned b0 = 0u, b1 = 0u;
  if (n1 < n) { b0 = a1; b1 = row_ptr[n1 + 1]; }
  unsigned rA = (a1 - a0 + 15u) >> 4, rB = (b1 - b0 + 15u) >> 4;
  unsigned R = rA > rB ? rA : rB;
  float accA[8] = {0.f, 0.f, 0.f, 0.f, 0.f, 0.f, 0.f, 0.f};
  float accB[8] = {0.f, 0.f, 0.f, 0.f, 0.f, 0.f, 0.f, 0.f};
  const uint4* pk4 = (const uint4*)pk;
  unsigned emax = (unsigned)(e - 1);
  uint2 cA = make_uint2(0u, 0u), cB = make_uint2(0u, 0u);
  float vA = 0.f, vB = 0.f;
  if (rA) {
    unsigned ix = a0 + eoff;
    vA = (ix < a1) ? 1.f : 0.f;
    unsigned cl = (ix < a1) ? ix : a0;
    cA = recs[cl < emax ? cl : emax];
  }
  if (rB) {
    unsigned ix = b0 + eoff;
    vB = (ix < b1) ? 1.f : 0.f;
    unsigned cl = (ix < b1) ? ix : b0;
    cB = recs[cl < emax ? cl : emax];
  }
  for (unsigned r = 0; r < R; ++r) {
    bool hA = r < rA, hB = r < rB;
    uint4 pA, pB;
    if (hA) pA = pk4[(size_t)cA.x * 4 + sub];
    if (hB) pB = pk4[(size_t)cB.x * 4 + sub];
    uint2 nAr = cA, nBr = cB;
    float nAv = 0.f, nBv = 0.f;
    if (r + 1 < rA) {
      unsigned ix = a0 + (r + 1) * 16 + eoff;
      nAv = (ix < a1) ? 1.f : 0.f;
      unsigned cl = (ix < a1) ? ix : a0;
      nAr = recs[cl < emax ? cl : emax];
    }
    if (r + 1 < rB) {
      unsigned ix = b0 + (r + 1) * 16 + eoff;
      nBv = (ix < b1) ? 1.f : 0.f;
      unsigned cl = (ix < b1) ? ix : b0;
      nBr = recs[cl < emax ? cl : emax];
    }
    if (hA) edge_acc(accA, pA, cA, vA, w0v, w1v, bbv);
    if (hB) edge_acc(accB, pB, cB, vB, w0v, w1v, bbv);
    cA = nAr; vA = nAv; cB = nBr; vB = nBv;
  }
#pragma unroll
  for (int j = 0; j < 8; ++j) {
    accA[j] += __shfl_xor(accA[j], 4, 64);
    accA[j] += __shfl_xor(accA[j], 8, 64);
    accA[j] += __shfl_xor(accA[j], 16, 64);
    accA[j] += __shfl_xor(accA[j], 32, 64);
    accB[j] += __shfl_xor(accB[j], 4, 64);
    accB[j] += __shfl_xor(accB[j], 8, 64);
    accB[j] += __shfl_xor(accB[j], 16, 64);
    accB[j] += __shfl_xor(accB[j], 32, 64);
  }
  if (lane < 4) {
    float4* o0 = (float4*)&agg[(size_t)n0 * H + lane * 8];
    o0[0] = make_float4(accA[0], accA[1], accA[2], accA[3]);
    o0[1] = make_float4(accA[4], accA[5], accA[6], accA[7]);
    if (n1 < n) {
      float4* o1 = (float4*)&agg[(size_t)n1 * H + lane * 8];
      o1[0] = make_float4(accB[0], accB[1], accB[2], accB[3]);
      o1[1] = make_float4(accB[4], accB[5], accB[6], accB[7]);
    }
  }
}

// node-per-lane update: o = relu([h,agg]@luw+lub); t = o@lnw+lnb; pk = fp8 pack.
// Weights are wave-uniform scalar loads: zero shuffles, zero LDS.
__global__ void __launch_bounds__(256) k_update(
    const float* __restrict__ h, const float* __restrict__ agg,
    const float* __restrict__ luw, const float* __restrict__ lub,
    const float* __restrict__ lnw, const float* __restrict__ lnb,
    float* __restrict__ hout, unsigned* __restrict__ pkout, int n) {
  int node = blockIdx.x * blockDim.x + threadIdx.x;
  if (node >= n) return;
  float hr[H], ar[H];
  const float4* h4 = (const float4*)(h + (size_t)node * H);
  const float4* a4 = (const float4*)(agg + (size_t)node * H);
#pragma unroll
  for (int q = 0; q < 8; ++q) {
    float4 v = h4[q];
    hr[4 * q] = v.x; hr[4 * q + 1] = v.y; hr[4 * q + 2] = v.z; hr[4 * q + 3] = v.w;
  }
#pragma unroll
  for (int q = 0; q < 8; ++q) {
    float4 v = a4[q];
    ar[4 * q] = v.x; ar[4 * q + 1] = v.y; ar[4 * q + 2] = v.z; ar[4 * q + 3] = v.w;
  }
  float o[H];
#pragma unroll
  for (int c = 0; c < H; ++c) o[c] = lub[c];
#pragma unroll
  for (int k = 0; k < H; ++k)
#pragma unroll
    for (int c = 0; c < H; ++c)
      o[c] = fmaf(hr[k], luw[k * H + c], o[c]);
#pragma unroll
  for (int k = 0; k < H; ++k)
#pragma unroll
    for (int c = 0; c < H; ++c)
      o[c] = fmaf(ar[k], luw[(H + k) * H + c], o[c]);
#pragma unroll
  for (int c = 0; c < H; ++c) o[c] = fmaxf(o[c], 0.f);
  float4* ho = (float4*)(hout + (size_t)node * H);
#pragma unroll
  for (int q = 0; q < 8; ++q)
    ho[q] = make_float4(o[4 * q], o[4 * q + 1], o[4 * q + 2], o[4 * q + 3]);
  if (pkout) {
    float t[H];
#pragma unroll
    for (int c = 0; c < H; ++c) t[c] = lnb[c];
#pragma unroll
    for (int k = 0; k < H; ++k)
#pragma unroll
      for (int c = 0; c < H; ++c)
        t[c] = fmaf(o[k], lnw[k * H + c], t[c]);
    unsigned dws[16];
#pragma unroll
    for (int d = 0; d < 16; ++d)
      dws[d] = pack4(o[2 * d], t[2 * d] - o[2 * d],
                     o[2 * d + 1], t[2 * d + 1] - o[2 * d + 1]);
    uint4* po = (uint4*)(pkout + (size_t)node * 16);
#pragma unroll
    for (int q = 0; q < 4; ++q)
      po[q] = make_uint4(dws[4 * q], dws[4 * q + 1], dws[4 * q + 2], dws[4 * q + 3]);
  }
}

// classifier: sigmoid(relu(h@c1+b1)@c2 + b2)
__global__ void k_cls(const float* __restrict__ h, const float* __restrict__ c1w,
                      const float* __restrict__ c1b, const float* __restrict__ c2w,
                      const float* __restrict__ c2b, float* __restrict__ out, int n) {
  __shared__ float sw[H * H];
  int tid = threadIdx.x;
  for (int i = tid; i < H * H; i += blockDim.x) sw[i] = c1w[i];
  __syncthreads();
  int gid = blockIdx.x * blockDim.x + tid;
  int node = gid >> 5, c = gid & 31;
  if (node >= n) return;
  float hv = h[node * H + c];
  float z = c1b[c];
#pragma unroll
  for (int k = 0; k < H; ++k)
    z = fmaf(__shfl(hv, k, 32), sw[k * H + c], z);
  z = fmaxf(z, 0.f);
  float r = z * c2w[c];
#pragma unroll
  for (int m = 16; m >= 1; m >>= 1)
    r += __shfl_xor(r, m, 32);
  if (c == 0) out[node] = 1.f / (1.f + expf(-(r + c2b[0])));
}

extern "C" void kernel_launch(void* const* d_in, const int* in_sizes, int n_in,
                              void* d_out, int out_size, void* d_ws, size_t ws_size,
                              hipStream_t stream) {
  const float* x         = (const float*)d_in[0];
  const float* edge_attr = (const float*)d_in[1];
  const int*   edge_index= (const int*)d_in[2];
  const float* Wn        = (const float*)d_in[3];
  const float* bn        = (const float*)d_in[4];
  const float* We        = (const float*)d_in[5];
  const float* be        = (const float*)d_in[6];
  const float* ln_w      = (const float*)d_in[7];
  const float* ln_b      = (const float*)d_in[8];
  const float* le_w      = (const float*)d_in[9];
  const float* le_b      = (const float*)d_in[10];
  const float* lu_w      = (const float*)d_in[11];
  const float* lu_b      = (const float*)d_in[12];
  const float* c1w       = (const float*)d_in[13];
  const float* c1b       = (const float*)d_in[14];
  const float* c2w       = (const float*)d_in[15];
  const float* c2b       = (const float*)d_in[16];

  const int N_ = in_sizes[0] / 5;
  const int E_ = in_sizes[1] / 2;
  const int L_ = in_sizes[7] / (H * H);
  const int* src = edge_index;
  const int* dst = edge_index + E_;

  char* ws = (char*)d_ws;
  size_t off = 0;
  auto alloc = [&](size_t bytes) -> void* {
    void* p = ws + off;
    off = (off + bytes + 255) & ~(size_t)255;
    return p;
  };
  float*    hA      = (float*)alloc((size_t)N_ * H * 4);
  float*    hB      = (float*)alloc((size_t)N_ * H * 4);
  unsigned* pkA     = (unsigned*)alloc((size_t)N_ * 16 * 4);
  unsigned* pkB     = (unsigned*)alloc((size_t)N_ * 16 * 4);
  float*    agg     = (float*)alloc((size_t)N_ * H * 4);
  unsigned* row_ptr = (unsigned*)alloc((size_t)(N_ + 1) * 4);
  unsigned* fill    = (unsigned*)alloc((size_t)N_ * 4);
  uint2*    recs    = (uint2*)alloc((size_t)E_ * 8);
  float*    W2      = (float*)alloc((size_t)L_ * 2 * H * 4);
  float*    b2      = (float*)alloc((size_t)L_ * H * 4);
  unsigned* bsum    = (unsigned*)alloc((size_t)SCB * 4);
  unsigned* boff    = (unsigned*)alloc((size_t)SCB * 4);

  const int tb = 256;
  const int nb = (N_ + SCB - 1) / SCB;
  hipMemsetAsync(fill, 0, (size_t)N_ * 4, stream);
  k_encode<<<(N_ * 32 + tb - 1) / tb, tb, 0, stream>>>(x, Wn, bn, ln_w, ln_b, hA, pkA, N_, 5);
  k_fold<<<(L_ * H + 63) / 64, 64, 0, stream>>>(We, be, le_w, le_b, W2, b2, L_);
  k_hist<<<(E_ + tb - 1) / tb, tb, 0, stream>>>(dst, fill, E_);
  k_scan1<<<nb, SCB, 0, stream>>>(fill, row_ptr, bsum, N_);
  k_scan2<<<1, SCB, 0, stream>>>(bsum, boff, row_ptr + N_, nb);
  k_scan3<<<(N_ + tb - 1) / tb, tb, 0, stream>>>(row_ptr, boff, fill, N_);
  k_scatter<<<(E_ + tb - 1) / tb, tb, 0, stream>>>(src, dst, edge_attr, fill, recs, E_);

  float* hc = hA;  float* hn = hB;
  unsigned* pc = pkA; unsigned* pn = pkB;
  for (int l = 0; l < L_; ++l) {
    bool last = (l == L_ - 1);
    k_gather<<<(N_ + 7) / 8, 256, 0, stream>>>(
        pc, row_ptr, recs, W2 + l * 2 * H, b2 + l * H, agg, N_, E_);
    k_update<<<(N_ + tb - 1) / tb, tb, 0, stream>>>(
        hc, agg, lu_w + (size_t)l * 2 * H * H, lu_b + (size_t)l * H,
        last ? nullptr : ln_w + (size_t)(l + 1) * H * H,
        last ? nullptr : ln_b + (size_t)(l + 1) * H,
        hn, last ? nullptr : pn, N_);
    float* tf = hc; hc = hn; hn = tf;
    unsigned* tp = pc; pc = pn; pn = tp;
  }
  k_cls<<<(N_ * 32 + tb - 1) / tb, tb, 0, stream>>>(hc, c1w, c1b, c2w, c2b, (float*)d_out, N_);
}

// Round 11
// 1923.142 us; speedup vs baseline: 2.1815x; 1.0796x over previous
//
#include <hip/hip_runtime.h>
#include <hip/hip_bf16.h>
#include <hip/hip_fp8.h>
#include <math.h>

#define H 32
#define SCB 1024

__device__ __forceinline__ unsigned f2bf(float f) {  // f32 -> bf16 bits, RNE
  unsigned u = __float_as_uint(f);
  return (u + 0x7fffu + ((u >> 16) & 1u)) >> 16;
}
__device__ __forceinline__ float bflo(unsigned p) { return __uint_as_float(p << 16); }
__device__ __forceinline__ float bfhi(unsigned p) { return __uint_as_float(p & 0xffff0000u); }

// f32 -> OCP e4m3fn byte (RNE, saturating) — proven encode path
__device__ __forceinline__ unsigned f2q(float f) {
  __hip_fp8_e4m3 q(f);
  return (unsigned)q.__x;
}
// manual e4m3fn -> f32 (fallback only)
__device__ __forceinline__ float q2f(unsigned b) {
  unsigned s = (b >> 7) & 1u, e = (b >> 3) & 15u, m = b & 7u;
  float vn = __uint_as_float((s << 31) | ((e + 120u) << 23) | (m << 20));
  float vs = __uint_as_float((s << 31) | 0x3f800000u) * ((float)(int)m * (1.0f / 512.0f));
  return (e == 0u) ? vs : vn;
}

// decode channel pair (x,u) from a dword of packed fp8 {x0,u0,x1,u1} (proven)
template <bool HI>
__device__ __forceinline__ void cvt2(unsigned dw, float& x, float& u) {
#if __has_builtin(__builtin_amdgcn_cvt_pk_f32_fp8)
  typedef float f32x2 __attribute__((ext_vector_type(2)));
  f32x2 v = __builtin_amdgcn_cvt_pk_f32_fp8((int)dw, HI);
  x = v[0]; u = v[1];
#else
  unsigned b = HI ? (dw >> 16) : dw;
  x = q2f(b & 255u); u = q2f((b >> 8) & 255u);
#endif
}

// pack {fp8(x0),fp8(u0),fp8(x1),fp8(u1)} into one dword — f2q only (proven)
__device__ __forceinline__ unsigned pack4(float x0, float u0, float x1, float u1) {
  return f2q(x0) | (f2q(u0) << 8) | (f2q(x1) << 16) | (f2q(u1) << 24);
}

// h = x@Wn+bn ; pk[n][16 dwords]: dword d = {x(2d),u(2d),x(2d+1),u(2d+1)} fp8
__global__ void k_encode(const float* __restrict__ x, const float* __restrict__ Wn,
                         const float* __restrict__ bn, const float* __restrict__ lnw0,
                         const float* __restrict__ lnb0, float* __restrict__ h,
                         unsigned* __restrict__ pk, int n, int fnode) {
  __shared__ float sw[H * H];
  int tid = threadIdx.x;
  for (int i = tid; i < H * H; i += blockDim.x) sw[i] = lnw0[i];
  __syncthreads();
  int gid = blockIdx.x * blockDim.x + tid;
  int node = gid >> 5, c = gid & 31;
  if (node >= n) return;
  float acc = bn[c];
  for (int k = 0; k < fnode; ++k)
    acc = fmaf(x[node * fnode + k], Wn[k * H + c], acc);
  h[node * H + c] = acc;
  float t = lnb0[c];
#pragma unroll
  for (int k = 0; k < H; ++k)
    t = fmaf(__shfl(acc, k, 32), sw[k * H + c], t);
  unsigned w = f2q(acc) | (f2q(t - acc) << 8);
  unsigned dw = w | (__shfl_xor(w, 1, 32) << 16);
  if (!(c & 1)) pk[node * 16 + (c >> 1)] = dw;
}

// W2[l] = We @ le_w[l]  ([2,H]) ; b2[l] = be @ le_w[l] + le_b[l]
__global__ void k_fold(const float* __restrict__ We, const float* __restrict__ be,
                       const float* __restrict__ lew, const float* __restrict__ leb,
                       float* __restrict__ W2, float* __restrict__ b2, int L) {
  int gid = blockIdx.x * blockDim.x + threadIdx.x;
  if (gid >= L * H) return;
  int l = gid >> 5, c = gid & 31;
  const float* lw = lew + (size_t)l * H * H;
  float a0 = 0.f, a1 = 0.f, bb = leb[l * H + c];
  for (int j = 0; j < H; ++j) {
    float w = lw[j * H + c];
    a0 = fmaf(We[j], w, a0);
    a1 = fmaf(We[H + j], w, a1);
    bb = fmaf(be[j], w, bb);
  }
  W2[l * 2 * H + c] = a0;
  W2[l * 2 * H + H + c] = a1;
  b2[l * H + c] = bb;
}

__global__ void k_hist(const int* __restrict__ dst, unsigned* __restrict__ cnt, int e) {
  int i = blockIdx.x * blockDim.x + threadIdx.x;
  if (i < e) atomicAdd(&cnt[dst[i]], 1u);
}

__global__ void k_scan1(const unsigned* __restrict__ cnt, unsigned* __restrict__ out,
                        unsigned* __restrict__ bsum, int n) {
  __shared__ unsigned s[SCB];
  int i = blockIdx.x * SCB + threadIdx.x;
  unsigned v = (i < n) ? cnt[i] : 0u;
  s[threadIdx.x] = v;
  __syncthreads();
  for (int off = 1; off < SCB; off <<= 1) {
    unsigned u = (threadIdx.x >= off) ? s[threadIdx.x - off] : 0u;
    __syncthreads();
    s[threadIdx.x] += u;
    __syncthreads();
  }
  if (i < n) out[i] = s[threadIdx.x] - v;
  if (threadIdx.x == SCB - 1) bsum[blockIdx.x] = s[SCB - 1];
}

__global__ void k_scan2(const unsigned* __restrict__ bsum, unsigned* __restrict__ boff,
                        unsigned* __restrict__ total_out, int nb) {
  __shared__ unsigned s[SCB];
  unsigned v = ((int)threadIdx.x < nb) ? bsum[threadIdx.x] : 0u;
  s[threadIdx.x] = v;
  __syncthreads();
  for (int off = 1; off < SCB; off <<= 1) {
    unsigned u = (threadIdx.x >= off) ? s[threadIdx.x - off] : 0u;
    __syncthreads();
    s[threadIdx.x] += u;
    __syncthreads();
  }
  if ((int)threadIdx.x < nb) boff[threadIdx.x] = s[threadIdx.x] - v;
  if (threadIdx.x == SCB - 1) *total_out = s[SCB - 1];
}

__global__ void k_scan3(unsigned* __restrict__ row_ptr, const unsigned* __restrict__ boff,
                        unsigned* __restrict__ fill, int n) {
  int i = blockIdx.x * blockDim.x + threadIdx.x;
  if (i >= n) return;
  unsigned v = row_ptr[i] + boff[i >> 10];
  row_ptr[i] = v;
  fill[i] = v;
}

// rec = {src, bf16(attr0) | bf16(attr1)<<16}
__global__ void k_scatter(const int* __restrict__ src, const int* __restrict__ dst,
                          const float* __restrict__ ea, unsigned* __restrict__ fill,
                          uint2* __restrict__ recs, int e) {
  int i = blockIdx.x * blockDim.x + threadIdx.x;
  if (i >= e) return;
  int d = dst[i];
  unsigned pos = atomicAdd(&fill[d], 1u);
  float2 a = ((const float2*)ea)[i];
  recs[pos] = make_uint2((unsigned)src[i], f2bf(a.x) | (f2bf(a.y) << 16));
}

__device__ __forceinline__ void edge_acc(float (&acc)[8], uint4 pv, uint2 rec, float v,
                                         const float (&w0v)[8], const float (&w1v)[8],
                                         const float (&bbv)[8]) {
  float a0 = bflo(rec.y), a1 = bfhi(rec.y);
  unsigned dws[4] = {pv.x, pv.y, pv.z, pv.w};
#pragma unroll
  for (int d = 0; d < 4; ++d) {
    float x0, u0, x1, u1;
    cvt2<false>(dws[d], x0, u0);
    cvt2<true>(dws[d], x1, u1);
    float e0 = fmaf(a0, w0v[2 * d], fmaf(a1, w1v[2 * d], bbv[2 * d]));
    float e1 = fmaf(a0, w0v[2 * d + 1], fmaf(a1, w1v[2 * d + 1], bbv[2 * d + 1]));
    acc[2 * d]     = fmaf(v, fmaf(e0, u0, x0), acc[2 * d]);
    acc[2 * d + 1] = fmaf(v, fmaf(e1, u1, x1), acc[2 * d + 1]);
  }
}

// gather-only: one wave = 4 interleaved dst nodes (breadth for memory concurrency).
// Per round: 4 independent pk gathers (16 edges each) + 4 rec prefetches in flight.
__global__ void __launch_bounds__(256) k_gather(
    const unsigned* __restrict__ pk, const unsigned* __restrict__ row_ptr,
    const uint2* __restrict__ recs, const float* __restrict__ W2l,
    const float* __restrict__ b2l, float* __restrict__ agg, int n, int e) {
  int tid = threadIdx.x;
  int lane = tid & 63;
  int gw = blockIdx.x * 4 + (tid >> 6);
  int n0 = gw * 4;
  if (n0 >= n) return;
  int sub = lane & 3;
  unsigned eoff = (unsigned)(lane >> 2);
  float w0v[8], w1v[8], bbv[8];
#pragma unroll
  for (int j = 0; j < 8; ++j) {
    int ch = sub * 8 + j;
    w0v[j] = W2l[ch]; w1v[j] = W2l[H + ch]; bbv[j] = b2l[ch];
  }
  unsigned rp[5];
#pragma unroll
  for (int i = 0; i < 5; ++i) {
    int idx = n0 + i;
    rp[i] = row_ptr[idx < n ? idx : n];
  }
  unsigned b0_0 = rp[0], b1_0 = rp[1];
  unsigned b0_1 = rp[1], b1_1 = rp[2];
  unsigned b0_2 = rp[2], b1_2 = rp[3];
  unsigned b0_3 = rp[3], b1_3 = rp[4];
  unsigned r_0 = (b1_0 - b0_0 + 15u) >> 4;
  unsigned r_1 = (b1_1 - b0_1 + 15u) >> 4;
  unsigned r_2 = (b1_2 - b0_2 + 15u) >> 4;
  unsigned r_3 = (b1_3 - b0_3 + 15u) >> 4;
  unsigned R = r_0;
  R = r_1 > R ? r_1 : R;
  R = r_2 > R ? r_2 : R;
  R = r_3 > R ? r_3 : R;
  float acc0[8] = {0,0,0,0,0,0,0,0};
  float acc1[8] = {0,0,0,0,0,0,0,0};
  float acc2[8] = {0,0,0,0,0,0,0,0};
  float acc3[8] = {0,0,0,0,0,0,0,0};
  const uint4* pk4 = (const uint4*)pk;
  unsigned emax = (unsigned)(e - 1);

#define RECLOAD(B0, B1, RR) \
    { unsigned ix = (B0) + (RR) * 16u + eoff; \
      unsigned cl = (ix < (B1)) ? ix : (B0); \
      cl = cl < emax ? cl : emax; \
      (void)0; }

  // prologue: load round-0 recs for all 4 nodes
  uint2 c_0, c_1, c_2, c_3;
  {
    unsigned ix, cl;
    ix = b0_0 + eoff; cl = (ix < b1_0) ? ix : b0_0; c_0 = recs[cl < emax ? cl : emax];
    ix = b0_1 + eoff; cl = (ix < b1_1) ? ix : b0_1; c_1 = recs[cl < emax ? cl : emax];
    ix = b0_2 + eoff; cl = (ix < b1_2) ? ix : b0_2; c_2 = recs[cl < emax ? cl : emax];
    ix = b0_3 + eoff; cl = (ix < b1_3) ? ix : b0_3; c_3 = recs[cl < emax ? cl : emax];
  }
  for (unsigned r = 0; r < R; ++r) {
    bool h0 = r < r_0, h1 = r < r_1, h2 = r < r_2, h3 = r < r_3;
    // issue all pk gathers back-to-back (independent)
    uint4 p_0, p_1, p_2, p_3;
    if (h0) p_0 = pk4[(size_t)c_0.x * 4 + sub];
    if (h1) p_1 = pk4[(size_t)c_1.x * 4 + sub];
    if (h2) p_2 = pk4[(size_t)c_2.x * 4 + sub];
    if (h3) p_3 = pk4[(size_t)c_3.x * 4 + sub];
    // prefetch next-round recs
    uint2 n_0 = c_0, n_1 = c_1, n_2 = c_2, n_3 = c_3;
    {
      unsigned ix, cl;
      if (r + 1 < r_0) { ix = b0_0 + (r + 1) * 16u + eoff; cl = (ix < b1_0) ? ix : b0_0; n_0 = recs[cl < emax ? cl : emax]; }
      if (r + 1 < r_1) { ix = b0_1 + (r + 1) * 16u + eoff; cl = (ix < b1_1) ? ix : b0_1; n_1 = recs[cl < emax ? cl : emax]; }
      if (r + 1 < r_2) { ix = b0_2 + (r + 1) * 16u + eoff; cl = (ix < b1_2) ? ix : b0_2; n_2 = recs[cl < emax ? cl : emax]; }
      if (r + 1 < r_3) { ix = b0_3 + (r + 1) * 16u + eoff; cl = (ix < b1_3) ? ix : b0_3; n_3 = recs[cl < emax ? cl : emax]; }
    }
    // compute (validity recomputed from scalars)
    unsigned rb = r << 4;
    if (h0) { float v = (b0_0 + rb + eoff < b1_0) ? 1.f : 0.f; edge_acc(acc0, p_0, c_0, v, w0v, w1v, bbv); }
    if (h1) { float v = (b0_1 + rb + eoff < b1_1) ? 1.f : 0.f; edge_acc(acc1, p_1, c_1, v, w0v, w1v, bbv); }
    if (h2) { float v = (b0_2 + rb + eoff < b1_2) ? 1.f : 0.f; edge_acc(acc2, p_2, c_2, v, w0v, w1v, bbv); }
    if (h3) { float v = (b0_3 + rb + eoff < b1_3) ? 1.f : 0.f; edge_acc(acc3, p_3, c_3, v, w0v, w1v, bbv); }
    c_0 = n_0; c_1 = n_1; c_2 = n_2; c_3 = n_3;
  }
#pragma unroll
  for (int j = 0; j < 8; ++j) {
    acc0[j] += __shfl_xor(acc0[j], 4, 64);
    acc0[j] += __shfl_xor(acc0[j], 8, 64);
    acc0[j] += __shfl_xor(acc0[j], 16, 64);
    acc0[j] += __shfl_xor(acc0[j], 32, 64);
    acc1[j] += __shfl_xor(acc1[j], 4, 64);
    acc1[j] += __shfl_xor(acc1[j], 8, 64);
    acc1[j] += __shfl_xor(acc1[j], 16, 64);
    acc1[j] += __shfl_xor(acc1[j], 32, 64);
    acc2[j] += __shfl_xor(acc2[j], 4, 64);
    acc2[j] += __shfl_xor(acc2[j], 8, 64);
    acc2[j] += __shfl_xor(acc2[j], 16, 64);
    acc2[j] += __shfl_xor(acc2[j], 32, 64);
    acc3[j] += __shfl_xor(acc3[j], 4, 64);
    acc3[j] += __shfl_xor(acc3[j], 8, 64);
    acc3[j] += __shfl_xor(acc3[j], 16, 64);
    acc3[j] += __shfl_xor(acc3[j], 32, 64);
  }
  if (lane < 4) {
    float4* o;
    if (n0 < n) {
      o = (float4*)&agg[(size_t)n0 * H + lane * 8];
      o[0] = make_float4(acc0[0], acc0[1], acc0[2], acc0[3]);
      o[1] = make_float4(acc0[4], acc0[5], acc0[6], acc0[7]);
    }
    if (n0 + 1 < n) {
      o = (float4*)&agg[(size_t)(n0 + 1) * H + lane * 8];
      o[0] = make_float4(acc1[0], acc1[1], acc1[2], acc1[3]);
      o[1] = make_float4(acc1[4], acc1[5], acc1[6], acc1[7]);
    }
    if (n0 + 2 < n) {
      o = (float4*)&agg[(size_t)(n0 + 2) * H + lane * 8];
      o[0] = make_float4(acc2[0], acc2[1], acc2[2], acc2[3]);
      o[1] = make_float4(acc2[4], acc2[5], acc2[6], acc2[7]);
    }
    if (n0 + 3 < n) {
      o = (float4*)&agg[(size_t)(n0 + 3) * H + lane * 8];
      o[0] = make_float4(acc3[0], acc3[1], acc3[2], acc3[3]);
      o[1] = make_float4(acc3[4], acc3[5], acc3[6], acc3[7]);
    }
  }
#undef RECLOAD
}

// node-per-lane update: o = relu([h,agg]@luw+lub); t = o@lnw+lnb; pk = fp8 pack.
__global__ void __launch_bounds__(256) k_update(
    const float* __restrict__ h, const float* __restrict__ agg,
    const float* __restrict__ luw, const float* __restrict__ lub,
    const float* __restrict__ lnw, const float* __restrict__ lnb,
    float* __restrict__ hout, unsigned* __restrict__ pkout, int n) {
  int node = blockIdx.x * blockDim.x + threadIdx.x;
  if (node >= n) return;
  float hr[H], ar[H];
  const float4* h4 = (const float4*)(h + (size_t)node * H);
  const float4* a4 = (const float4*)(agg + (size_t)node * H);
#pragma unroll
  for (int q = 0; q < 8; ++q) {
    float4 v = h4[q];
    hr[4 * q] = v.x; hr[4 * q + 1] = v.y; hr[4 * q + 2] = v.z; hr[4 * q + 3] = v.w;
  }
#pragma unroll
  for (int q = 0; q < 8; ++q) {
    float4 v = a4[q];
    ar[4 * q] = v.x; ar[4 * q + 1] = v.y; ar[4 * q + 2] = v.z; ar[4 * q + 3] = v.w;
  }
  float o[H];
#pragma unroll
  for (int c = 0; c < H; ++c) o[c] = lub[c];
#pragma unroll
  for (int k = 0; k < H; ++k)
#pragma unroll
    for (int c = 0; c < H; ++c)
      o[c] = fmaf(hr[k], luw[k * H + c], o[c]);
#pragma unroll
  for (int k = 0; k < H; ++k)
#pragma unroll
    for (int c = 0; c < H; ++c)
      o[c] = fmaf(ar[k], luw[(H + k) * H + c], o[c]);
#pragma unroll
  for (int c = 0; c < H; ++c) o[c] = fmaxf(o[c], 0.f);
  float4* ho = (float4*)(hout + (size_t)node * H);
#pragma unroll
  for (int q = 0; q < 8; ++q)
    ho[q] = make_float4(o[4 * q], o[4 * q + 1], o[4 * q + 2], o[4 * q + 3]);
  if (pkout) {
    float t[H];
#pragma unroll
    for (int c = 0; c < H; ++c) t[c] = lnb[c];
#pragma unroll
    for (int k = 0; k < H; ++k)
#pragma unroll
      for (int c = 0; c < H; ++c)
        t[c] = fmaf(o[k], lnw[k * H + c], t[c]);
    unsigned dws[16];
#pragma unroll
    for (int d = 0; d < 16; ++d)
      dws[d] = pack4(o[2 * d], t[2 * d] - o[2 * d],
                     o[2 * d + 1], t[2 * d + 1] - o[2 * d + 1]);
    uint4* po = (uint4*)(pkout + (size_t)node * 16);
#pragma unroll
    for (int q = 0; q < 4; ++q)
      po[q] = make_uint4(dws[4 * q], dws[4 * q + 1], dws[4 * q + 2], dws[4 * q + 3]);
  }
}

// classifier: sigmoid(relu(h@c1+b1)@c2 + b2)
__global__ void k_cls(const float* __restrict__ h, const float* __restrict__ c1w,
                      const float* __restrict__ c1b, const float* __restrict__ c2w,
                      const float* __restrict__ c2b, float* __restrict__ out, int n) {
  __shared__ float sw[H * H];
  int tid = threadIdx.x;
  for (int i = tid; i < H * H; i += blockDim.x) sw[i] = c1w[i];
  __syncthreads();
  int gid = blockIdx.x * blockDim.x + tid;
  int node = gid >> 5, c = gid & 31;
  if (node >= n) return;
  float hv = h[node * H + c];
  float z = c1b[c];
#pragma unroll
  for (int k = 0; k < H; ++k)
    z = fmaf(__shfl(hv, k, 32), sw[k * H + c], z);
  z = fmaxf(z, 0.f);
  float r = z * c2w[c];
#pragma unroll
  for (int m = 16; m >= 1; m >>= 1)
    r += __shfl_xor(r, m, 32);
  if (c == 0) out[node] = 1.f / (1.f + expf(-(r + c2b[0])));
}

extern "C" void kernel_launch(void* const* d_in, const int* in_sizes, int n_in,
                              void* d_out, int out_size, void* d_ws, size_t ws_size,
                              hipStream_t stream) {
  const float* x         = (const float*)d_in[0];
  const float* edge_attr = (const float*)d_in[1];
  const int*   edge_index= (const int*)d_in[2];
  const float* Wn        = (const float*)d_in[3];
  const float* bn        = (const float*)d_in[4];
  const float* We        = (const float*)d_in[5];
  const float* be        = (const float*)d_in[6];
  const float* ln_w      = (const float*)d_in[7];
  const float* ln_b      = (const float*)d_in[8];
  const float* le_w      = (const float*)d_in[9];
  const float* le_b      = (const float*)d_in[10];
  const float* lu_w      = (const float*)d_in[11];
  const float* lu_b      = (const float*)d_in[12];
  const float* c1w       = (const float*)d_in[13];
  const float* c1b       = (const float*)d_in[14];
  const float* c2w       = (const float*)d_in[15];
  const float* c2b       = (const float*)d_in[16];

  const int N_ = in_sizes[0] / 5;
  const int E_ = in_sizes[1] / 2;
  const int L_ = in_sizes[7] / (H * H);
  const int* src = edge_index;
  const int* dst = edge_index + E_;

  char* ws = (char*)d_ws;
  size_t off = 0;
  auto alloc = [&](size_t bytes) -> void* {
    void* p = ws + off;
    off = (off + bytes + 255) & ~(size_t)255;
    return p;
  };
  float*    hA      = (float*)alloc((size_t)N_ * H * 4);
  float*    hB      = (float*)alloc((size_t)N_ * H * 4);
  unsigned* pkA     = (unsigned*)alloc((size_t)N_ * 16 * 4);
  unsigned* pkB     = (unsigned*)alloc((size_t)N_ * 16 * 4);
  float*    agg     = (float*)alloc((size_t)N_ * H * 4);
  unsigned* row_ptr = (unsigned*)alloc((size_t)(N_ + 1) * 4);
  unsigned* fill    = (unsigned*)alloc((size_t)N_ * 4);
  uint2*    recs    = (uint2*)alloc((size_t)E_ * 8);
  float*    W2      = (float*)alloc((size_t)L_ * 2 * H * 4);
  float*    b2      = (float*)alloc((size_t)L_ * H * 4);
  unsigned* bsum    = (unsigned*)alloc((size_t)SCB * 4);
  unsigned* boff    = (unsigned*)alloc((size_t)SCB * 4);

  const int tb = 256;
  const int nb = (N_ + SCB - 1) / SCB;
  hipMemsetAsync(fill, 0, (size_t)N_ * 4, stream);
  k_encode<<<(N_ * 32 + tb - 1) / tb, tb, 0, stream>>>(x, Wn, bn, ln_w, ln_b, hA, pkA, N_, 5);
  k_fold<<<(L_ * H + 63) / 64, 64, 0, stream>>>(We, be, le_w, le_b, W2, b2, L_);
  k_hist<<<(E_ + tb - 1) / tb, tb, 0, stream>>>(dst, fill, E_);
  k_scan1<<<nb, SCB, 0, stream>>>(fill, row_ptr, bsum, N_);
  k_scan2<<<1, SCB, 0, stream>>>(bsum, boff, row_ptr + N_, nb);
  k_scan3<<<(N_ + tb - 1) / tb, tb, 0, stream>>>(row_ptr, boff, fill, N_);
  k_scatter<<<(E_ + tb - 1) / tb, tb, 0, stream>>>(src, dst, edge_attr, fill, recs, E_);

  float* hc = hA;  float* hn = hB;
  unsigned* pc = pkA; unsigned* pn = pkB;
  for (int l = 0; l < L_; ++l) {
    bool last = (l == L_ - 1);
    k_gather<<<(N_ + 15) / 16, 256, 0, stream>>>(
        pc, row_ptr, recs, W2 + l * 2 * H, b2 + l * H, agg, N_, E_);
    k_update<<<(N_ + tb - 1) / tb, tb, 0, stream>>>(
        hc, agg, lu_w + (size_t)l * 2 * H * H, lu_b + (size_t)l * H,
        last ? nullptr : ln_w + (size_t)(l + 1) * H * H,
        last ? nullptr : ln_b + (size_t)(l + 1) * H,
        hn, last ? nullptr : pn, N_);
    float* tf = hc; hc = hn; hn = tf;
    unsigned* tp = pc; pc = pn; pn = tp;
  }
  k_cls<<<(N_ * 32 + tb - 1) / tb, tb, 0, stream>>>(hc, c1w, c1b, c2w, c2b, (float*)d_out, N_);
}